// Round 5
// baseline (251.940 us; speedup 1.0000x reference)
//
#include <hip/hip_runtime.h>
#include <hip/hip_bf16.h>
#include <hip/hip_cooperative_groups.h>
#include <math.h>

namespace cg = cooperative_groups;

#define NA 2048   // agents (2^11)
#define TT 20     // timesteps
#define KK 32     // neighbors
#define CC 32     // in channels
#define OO 64     // out channels / hidden
#define GG 256    // 4*OO gates

#define NGRP (NA / 16)        // 128 agent-groups (lstm phase blocks)
#define NGATH (NA * TT / 16)  // 2560 gather row-groups
#define NB 512                // cooperative grid: only 2 blocks/CU needed
#define NCU 256               // MI355X CUs

typedef __attribute__((ext_vector_type(8))) short short8;
typedef __attribute__((ext_vector_type(4))) float float4v;

__device__ __forceinline__ float fast_rcp(float x) {
    return __builtin_amdgcn_rcpf(x);
}
__device__ __forceinline__ float sigm(float x) {
    return fast_rcp(1.f + __expf(-x));
}
__device__ __forceinline__ float tanh_fast(float x) {
    return 1.f - 2.f * fast_rcp(1.f + __expf(2.f * x));
}
// bf16 RNE on raw bits (ties-to-even; NaN not expected here).
__device__ __forceinline__ unsigned cvt_rne(float f) {
    unsigned u = __float_as_uint(f);
    return (u + 0x7FFFu + ((u >> 16) & 1u)) >> 16;
}
__device__ __forceinline__ unsigned pack2(float a, float b) {
    return cvt_rne(a) | (cvt_rne(b) << 16);
}
__device__ __forceinline__ float bf_lo(unsigned u) {
    return __uint_as_float(u << 16);
}
__device__ __forceinline__ float bf_hi(unsigned u) {
    return __uint_as_float(u & 0xffff0000u);
}

// ======================= cooperative mega-kernel =======================
// proj -> grid.sync -> gather -> grid.sync -> lstm. Phase bodies verbatim
// the proven R2 standalone kernels; only launch structure differs.
__global__ __launch_bounds__(256, 2) void mega_kernel(
    const float* __restrict__ x, const int* __restrict__ A,
    const float* __restrict__ conv_w, const float* __restrict__ conv_b,
    const float* __restrict__ w_ih, const float* __restrict__ w_hh,
    const float* __restrict__ b_ih, const float* __restrict__ b_hh,
    __hip_bfloat16* __restrict__ P, unsigned* __restrict__ featw,
    unsigned short* __restrict__ wihb, unsigned short* __restrict__ whhb,
    float* __restrict__ biasT, float* __restrict__ out)
{
    cg::grid_group grid = cg::this_grid();
    const int tid = threadIdx.x;
    const int lane = tid & 63;
    const int wv = tid >> 6;

    __shared__ int A_sh[4][128];                               // gather
    __shared__ __align__(16) unsigned short h_sh[2][16 * 72];  // lstm dbuf

    // ---------------- phase 1: prep (last block) + proj (all, strided)
    if (blockIdx.x == NB - 1) {
        for (int e = tid; e < 4 * OO * OO; e += 256) {
            wihb[e] = (unsigned short)cvt_rne(w_ih[e]);
            whhb[e] = (unsigned short)cvt_rne(w_hh[e]);
        }
        float bj = b_ih[tid] + b_hh[tid];
        #pragma unroll
        for (int o = 0; o < OO; o += 4) {
            float4 cb = *(const float4*)(conv_b + o);
            float4 wr = *(const float4*)(w_ih + (size_t)tid * OO + o);
            bj = fmaf(cb.x, wr.x, bj); bj = fmaf(cb.y, wr.y, bj);
            bj = fmaf(cb.z, wr.z, bj); bj = fmaf(cb.w, wr.w, bj);
        }
        biasT[tid] = bj;
    }
    {
        float w[CC];
        #pragma unroll
        for (int c = 0; c < CC; c += 4) {
            float4 v = *(const float4*)(conv_w + lane * CC + c);
            w[c] = v.x; w[c + 1] = v.y; w[c + 2] = v.z; w[c + 3] = v.w;
        }
        for (int item = blockIdx.x; item < NGATH; item += NB) {
            const int rbase = item * 16 + wv * 4;
            #pragma unroll
            for (int i = 0; i < 4; ++i) {
                int r = rbase + i;            // r = n*TT + t (x row order)
                const float* xr = x + (size_t)r * CC;
                float a0 = 0.f, a1 = 0.f;
                #pragma unroll
                for (int c = 0; c < CC; c += 8) {
                    float4 v = *(const float4*)(xr + c);
                    float4 u = *(const float4*)(xr + c + 4);
                    a0 = fmaf(v.x, w[c], a0);     a0 = fmaf(v.y, w[c + 1], a0);
                    a0 = fmaf(v.z, w[c + 2], a0); a0 = fmaf(v.w, w[c + 3], a0);
                    a1 = fmaf(u.x, w[c + 4], a1); a1 = fmaf(u.y, w[c + 5], a1);
                    a1 = fmaf(u.z, w[c + 6], a1); a1 = fmaf(u.w, w[c + 7], a1);
                }
                int n = r / TT;
                int t = r - n * TT;
                ((unsigned short*)P)[(((size_t)t << 11) + n) * OO + lane] =
                    (unsigned short)cvt_rne(a0 + a1);
            }
        }
    }
    grid.sync();   // P / weights visible everywhere

    // ---------------- phase 2: gather (proven body, strided)
    for (int item = blockIdx.x; item < NGATH; item += NB) {
        // stride NB == 0 mod 8 -> item&7 stable -> XCD partition kept
        const int bs = (item & 7) * 320 + (item >> 3);
        const int r0 = bs << 4;               // 16 rows, r = t*NA + n
        const int t = r0 >> 11;               // never crosses a t-slab
        const unsigned short* Pt =
            (const unsigned short*)P + ((size_t)t << 17);

        const int rw = r0 + wv * 4;           // wave's first row
        // same-wave DS ordering: write then read A_sh[wv], no barrier
        ((int2*)A_sh[wv])[lane] = ((const int2*)(A + ((size_t)rw << 5)))[lane];

        const int i_row = lane >> 4;          // 0..3: row within wave
        const int oc8 = lane & 15;            // 8B chunk (4 channels)
        const char* plane = (const char*)Pt + oc8 * 8;
        const int* myA = &A_sh[wv][i_row * 32];

        const int nself = (rw + i_row) & (NA - 1);
        const uint2 su = *(const uint2*)(plane + ((size_t)nself << 7));

        float m0 = -INFINITY, m1 = -INFINITY;
        float m2 = -INFINITY, m3 = -INFINITY;
        #pragma unroll
        for (int bb = 0; bb < 2; ++bb) {
            int idx[16];
            #pragma unroll
            for (int g = 0; g < 16; ++g)      // broadcast ds_read_b32
                idx[g] = myA[bb * 16 + g];
            uint2 uv[16];                     // 32 VGPRs in-flight payload
            #pragma unroll
            for (int g = 0; g < 16; ++g)
                uv[g] = *(const uint2*)(plane + ((size_t)idx[g] << 7));
            #pragma unroll
            for (int g = 0; g < 16; ++g) {
                m0 = fmaxf(m0, bf_lo(uv[g].x)); m1 = fmaxf(m1, bf_hi(uv[g].x));
                m2 = fmaxf(m2, bf_lo(uv[g].y)); m3 = fmaxf(m3, bf_hi(uv[g].y));
            }
        }
        uint2 pk;
        pk.x = pack2(m0 - bf_lo(su.x), m1 - bf_hi(su.x));
        pk.y = pack2(m2 - bf_lo(su.y), m3 - bf_hi(su.y));
        *(uint2*)&featw[((size_t)(rw + i_row) << 5) + oc8 * 2] = pk;
    }
    grid.sync();   // featw visible everywhere

    // ---------------- phase 3: lstm (blocks 0..NGRP-1; proven R2 body)
    if (blockIdx.x >= NGRP) return;

    const int l15 = lane & 15;
    const int q = lane >> 4;
    const int a0 = blockIdx.x * 16;
    const int ch = wv * 16 + l15;     // this lane's gate/hidden channel

    short8 bfI[4][2], bfH[4][2];
    #pragma unroll
    for (int g = 0; g < 4; ++g) {
        int row = g * 64 + ch;
        #pragma unroll
        for (int ks = 0; ks < 2; ++ks) {
            bfI[g][ks] =
                *(const short8*)(wihb + ((size_t)row << 6) + ks * 32 + q * 8);
            bfH[g][ks] =
                *(const short8*)(whhb + ((size_t)row << 6) + ks * 32 + q * 8);
        }
    }
    float bias_g[4];
    #pragma unroll
    for (int g = 0; g < 4; ++g)
        bias_g[g] = biasT[g * 64 + ch];

    for (int e = tid; e < 16 * 72 / 2; e += 256)
        ((unsigned*)h_sh[0])[e] = 0u;

    float cst[4] = {0.f, 0.f, 0.f, 0.f};
    const unsigned short* feat = (const unsigned short*)featw;

    short8 ff[2];
    #pragma unroll
    for (int ks = 0; ks < 2; ++ks)
        ff[ks] = *(const short8*)(
            feat + (((size_t)a0 + l15) << 6) + ks * 32 + q * 8);

    __syncthreads();  // h_sh[0] ready

    for (int t = 0; t < TT; ++t) {
        short8 ah[2];
        #pragma unroll
        for (int ks = 0; ks < 2; ++ks)
            ah[ks] = *(const short8*)(
                &h_sh[t & 1][l15 * 72 + ks * 32 + q * 8]);

        float4v acc[4] = {{0.f, 0.f, 0.f, 0.f}, {0.f, 0.f, 0.f, 0.f},
                          {0.f, 0.f, 0.f, 0.f}, {0.f, 0.f, 0.f, 0.f}};
        #pragma unroll
        for (int ks = 0; ks < 2; ++ks) {
            #pragma unroll
            for (int g = 0; g < 4; ++g) {
                acc[g] = __builtin_amdgcn_mfma_f32_16x16x32_bf16(
                    ff[ks], bfI[g][ks], acc[g], 0, 0, 0);
                acc[g] = __builtin_amdgcn_mfma_f32_16x16x32_bf16(
                    ah[ks], bfH[g][ks], acc[g], 0, 0, 0);
            }
        }

        short8 ffn[2];
        int tn = (t + 1 < TT) ? t + 1 : t;
        #pragma unroll
        for (int ks = 0; ks < 2; ++ks)
            ffn[ks] = *(const short8*)(
                feat + ((((size_t)tn << 11) + a0 + l15) << 6) + ks * 32 + q * 8);

        #pragma unroll
        for (int rg = 0; rg < 4; ++rg) {
            float gi = acc[0][rg] + bias_g[0];
            float gf = acc[1][rg] + bias_g[1];
            float gz = acc[2][rg] + bias_g[2];
            float go = acc[3][rg] + bias_g[3];
            float ig = sigm(gi);
            float fg = sigm(gf);
            float zg = tanh_fast(gz);
            float og = sigm(go);
            cst[rg] = fmaf(fg, cst[rg], ig * zg);
            float hv = og * tanh_fast(cst[rg]);
            int agent = q * 4 + rg;
            h_sh[(t + 1) & 1][agent * 72 + ch] = (unsigned short)cvt_rne(hv);
            out[(((size_t)(a0 + agent) * TT + t) << 6) + ch] = hv;
            if (t == TT - 1) {
                size_t hb = (size_t)NA * TT * OO;
                out[hb + ((size_t)(a0 + agent) << 6) + ch] = hv;
                out[hb + ((size_t)NA << 6) + ((size_t)(a0 + agent) << 6) + ch] =
                    cst[rg];
            }
        }
        __syncthreads();
        ff[0] = ffn[0]; ff[1] = ffn[1];
    }
}

// ======================= proven R2 fallback kernels =======================
__global__ __launch_bounds__(256) void proj_kernel(
    const float* __restrict__ x, const float* __restrict__ conv_w,
    const float* __restrict__ conv_b, const float* __restrict__ w_ih,
    const float* __restrict__ w_hh, const float* __restrict__ b_ih,
    const float* __restrict__ b_hh,
    __hip_bfloat16* __restrict__ P, unsigned short* __restrict__ wihb,
    unsigned short* __restrict__ whhb, float* __restrict__ biasT)
{
    const int tid = threadIdx.x;
    if (blockIdx.x == 0) {   // prep block
        for (int e = tid; e < 4 * OO * OO; e += 256) {
            wihb[e] = (unsigned short)cvt_rne(w_ih[e]);
            whhb[e] = (unsigned short)cvt_rne(w_hh[e]);
        }
        float bj = b_ih[tid] + b_hh[tid];
        #pragma unroll
        for (int o = 0; o < OO; o += 4) {
            float4 cb = *(const float4*)(conv_b + o);
            float4 wr = *(const float4*)(w_ih + (size_t)tid * OO + o);
            bj = fmaf(cb.x, wr.x, bj); bj = fmaf(cb.y, wr.y, bj);
            bj = fmaf(cb.z, wr.z, bj); bj = fmaf(cb.w, wr.w, bj);
        }
        biasT[tid] = bj;
        return;
    }
    const int lane = tid & 63;
    const int wv = tid >> 6;
    float w[CC];
    #pragma unroll
    for (int c = 0; c < CC; c += 4) {
        float4 v = *(const float4*)(conv_w + lane * CC + c);
        w[c] = v.x; w[c + 1] = v.y; w[c + 2] = v.z; w[c + 3] = v.w;
    }
    const int rbase = (blockIdx.x - 1) * 16 + wv * 4;
    #pragma unroll
    for (int i = 0; i < 4; ++i) {
        int r = rbase + i;
        const float* xr = x + (size_t)r * CC;
        float a0 = 0.f, a1 = 0.f;
        #pragma unroll
        for (int c = 0; c < CC; c += 8) {
            float4 v = *(const float4*)(xr + c);
            float4 u = *(const float4*)(xr + c + 4);
            a0 = fmaf(v.x, w[c], a0);     a0 = fmaf(v.y, w[c + 1], a0);
            a0 = fmaf(v.z, w[c + 2], a0); a0 = fmaf(v.w, w[c + 3], a0);
            a1 = fmaf(u.x, w[c + 4], a1); a1 = fmaf(u.y, w[c + 5], a1);
            a1 = fmaf(u.z, w[c + 6], a1); a1 = fmaf(u.w, w[c + 7], a1);
        }
        int n = r / TT;
        int t = r - n * TT;
        ((unsigned short*)P)[(((size_t)t << 11) + n) * OO + lane] =
            (unsigned short)cvt_rne(a0 + a1);
    }
}

__global__ __launch_bounds__(256, 4) void gather_kernel(
    const __hip_bfloat16* __restrict__ P, const int* __restrict__ A,
    unsigned* __restrict__ featw)
{
    __shared__ int A_sh[4][128];
    const int tid = threadIdx.x;
    const int lane = tid & 63;
    const int wv = tid >> 6;
    const int bs = (blockIdx.x & 7) * 320 + (blockIdx.x >> 3);  // XCD swizzle
    const int r0 = bs << 4;
    const int t = r0 >> 11;
    const unsigned short* Pt = (const unsigned short*)P + ((size_t)t << 17);

    const int rw = r0 + wv * 4;
    ((int2*)A_sh[wv])[lane] = ((const int2*)(A + ((size_t)rw << 5)))[lane];

    const int i_row = lane >> 4;
    const int oc8 = lane & 15;
    const char* plane = (const char*)Pt + oc8 * 8;
    const int* myA = &A_sh[wv][i_row * 32];

    const int nself = (rw + i_row) & (NA - 1);
    const uint2 su = *(const uint2*)(plane + ((size_t)nself << 7));

    float m0 = -INFINITY, m1 = -INFINITY, m2 = -INFINITY, m3 = -INFINITY;
    #pragma unroll
    for (int bb = 0; bb < 2; ++bb) {
        int idx[16];
        #pragma unroll
        for (int g = 0; g < 16; ++g)
            idx[g] = myA[bb * 16 + g];
        uint2 uv[16];
        #pragma unroll
        for (int g = 0; g < 16; ++g)
            uv[g] = *(const uint2*)(plane + ((size_t)idx[g] << 7));
        #pragma unroll
        for (int g = 0; g < 16; ++g) {
            m0 = fmaxf(m0, bf_lo(uv[g].x)); m1 = fmaxf(m1, bf_hi(uv[g].x));
            m2 = fmaxf(m2, bf_lo(uv[g].y)); m3 = fmaxf(m3, bf_hi(uv[g].y));
        }
    }
    uint2 pk;
    pk.x = pack2(m0 - bf_lo(su.x), m1 - bf_hi(su.x));
    pk.y = pack2(m2 - bf_lo(su.y), m3 - bf_hi(su.y));
    *(uint2*)&featw[((size_t)(rw + i_row) << 5) + oc8 * 2] = pk;
}

__global__ __launch_bounds__(256) void lstm_kernel(
    const unsigned short* __restrict__ feat,
    const unsigned short* __restrict__ wihb,
    const unsigned short* __restrict__ whhb,
    const float* __restrict__ biasT, float* __restrict__ out)
{
    const int tid = threadIdx.x;
    const int lane = tid & 63;
    const int wv = tid >> 6;
    const int l15 = lane & 15;
    const int q = lane >> 4;
    const int a0 = blockIdx.x * 16;
    const int ch = wv * 16 + l15;

    short8 bfI[4][2], bfH[4][2];
    #pragma unroll
    for (int g = 0; g < 4; ++g) {
        int row = g * 64 + ch;
        #pragma unroll
        for (int ks = 0; ks < 2; ++ks) {
            bfI[g][ks] =
                *(const short8*)(wihb + ((size_t)row << 6) + ks * 32 + q * 8);
            bfH[g][ks] =
                *(const short8*)(whhb + ((size_t)row << 6) + ks * 32 + q * 8);
        }
    }
    float bias_g[4];
    #pragma unroll
    for (int g = 0; g < 4; ++g)
        bias_g[g] = biasT[g * 64 + ch];

    __shared__ __align__(16) unsigned short h_sh[2][16 * 72];

    for (int e = tid; e < 16 * 72 / 2; e += 256)
        ((unsigned*)h_sh[0])[e] = 0u;

    float cst[4] = {0.f, 0.f, 0.f, 0.f};

    short8 ff[2];
    #pragma unroll
    for (int ks = 0; ks < 2; ++ks)
        ff[ks] = *(const short8*)(
            feat + (((size_t)a0 + l15) << 6) + ks * 32 + q * 8);

    __syncthreads();

    for (int t = 0; t < TT; ++t) {
        short8 ah[2];
        #pragma unroll
        for (int ks = 0; ks < 2; ++ks)
            ah[ks] = *(const short8*)(
                &h_sh[t & 1][l15 * 72 + ks * 32 + q * 8]);

        float4v acc[4] = {{0.f, 0.f, 0.f, 0.f}, {0.f, 0.f, 0.f, 0.f},
                          {0.f, 0.f, 0.f, 0.f}, {0.f, 0.f, 0.f, 0.f}};
        #pragma unroll
        for (int ks = 0; ks < 2; ++ks) {
            #pragma unroll
            for (int g = 0; g < 4; ++g) {
                acc[g] = __builtin_amdgcn_mfma_f32_16x16x32_bf16(
                    ff[ks], bfI[g][ks], acc[g], 0, 0, 0);
                acc[g] = __builtin_amdgcn_mfma_f32_16x16x32_bf16(
                    ah[ks], bfH[g][ks], acc[g], 0, 0, 0);
            }
        }

        short8 ffn[2];
        int tn = (t + 1 < TT) ? t + 1 : t;
        #pragma unroll
        for (int ks = 0; ks < 2; ++ks)
            ffn[ks] = *(const short8*)(
                feat + ((((size_t)tn << 11) + a0 + l15) << 6) + ks * 32 + q * 8);

        #pragma unroll
        for (int rg = 0; rg < 4; ++rg) {
            float gi = acc[0][rg] + bias_g[0];
            float gf = acc[1][rg] + bias_g[1];
            float gz = acc[2][rg] + bias_g[2];
            float go = acc[3][rg] + bias_g[3];
            float ig = sigm(gi);
            float fg = sigm(gf);
            float zg = tanh_fast(gz);
            float og = sigm(go);
            cst[rg] = fmaf(fg, cst[rg], ig * zg);
            float hv = og * tanh_fast(cst[rg]);
            int agent = q * 4 + rg;
            h_sh[(t + 1) & 1][agent * 72 + ch] = (unsigned short)cvt_rne(hv);
            out[(((size_t)(a0 + agent) * TT + t) << 6) + ch] = hv;
            if (t == TT - 1) {
                size_t hb = (size_t)NA * TT * OO;
                out[hb + ((size_t)(a0 + agent) << 6) + ch] = hv;
                out[hb + ((size_t)NA << 6) + ((size_t)(a0 + agent) << 6) + ch] =
                    cst[rg];
            }
        }
        __syncthreads();
        ff[0] = ffn[0]; ff[1] = ffn[1];
    }
}

extern "C" void kernel_launch(void* const* d_in, const int* in_sizes, int n_in,
                              void* d_out, int out_size, void* d_ws, size_t ws_size,
                              hipStream_t stream) {
    const float* x      = (const float*)d_in[0];
    const int*   A      = (const int*)  d_in[1];
    const float* conv_w = (const float*)d_in[2];
    const float* conv_b = (const float*)d_in[3];
    const float* w_ih   = (const float*)d_in[4];
    const float* w_hh   = (const float*)d_in[5];
    const float* b_ih   = (const float*)d_in[6];
    const float* b_hh   = (const float*)d_in[7];
    float* out = (float*)d_out;

    char* ws = (char*)d_ws;
    __hip_bfloat16* P  = (__hip_bfloat16*)ws;                    // 5.25 MB
    size_t offF = (size_t)TT * NA * OO * 2;
    unsigned* featw = (unsigned*)(ws + offF);                    // 5.25 MB
    size_t offW = offF + (size_t)TT * NA * OO * 2;
    unsigned short* wihb = (unsigned short*)(ws + offW);         // 32 KB
    unsigned short* whhb = wihb + 4 * OO * OO;                   // 32 KB
    float* biasT = (float*)(whhb + 4 * OO * OO);                 // 1 KB

    // Decide once whether the cooperative path is viable (co-residency).
    static int coop_state = 0;   // 0 = unknown, 1 = yes, -1 = no
    if (coop_state == 0) {
        int maxb = 0;
        hipError_t e = hipOccupancyMaxActiveBlocksPerMultiprocessor(
            &maxb, (const void*)mega_kernel, 256, 0);
        coop_state = (e == hipSuccess && maxb * NCU >= NB) ? 1 : -1;
    }

    bool done = false;
    if (coop_state == 1) {
        void* args[] = {&x, &A, &conv_w, &conv_b, &w_ih, &w_hh, &b_ih, &b_hh,
                        &P, &featw, &wihb, &whhb, &biasT, &out};
        hipError_t e = hipLaunchCooperativeKernel(
            (const void*)mega_kernel, dim3(NB), dim3(256), args, 0, stream);
        if (e == hipSuccess) {
            done = true;
        } else {
            coop_state = -1;   // don't retry on future captures
        }
    }

    if (!done) {   // proven R2 three-kernel path
        hipLaunchKernelGGL(proj_kernel, dim3(NGATH + 1), dim3(256), 0, stream,
                           x, conv_w, conv_b, w_ih, w_hh, b_ih, b_hh,
                           P, wihb, whhb, biasT);
        hipLaunchKernelGGL(gather_kernel, dim3(NGATH), dim3(256), 0, stream,
                           P, A, featw);
        hipLaunchKernelGGL(lstm_kernel, dim3(NA / 16), dim3(256), 0, stream,
                           (const unsigned short*)featw, wihb, whhb, biasT, out);
    }
}

// Round 6
// 133.317 us; speedup vs baseline: 1.8898x; 1.8898x over previous
//
#include <hip/hip_runtime.h>
#include <hip/hip_bf16.h>
#include <math.h>

#define NA 2048   // agents (2^11)
#define TT 20     // timesteps
#define KK 32     // neighbors
#define CC 32     // in channels
#define OO 64     // out channels / hidden
#define GG 256    // 4*OO gates

typedef __attribute__((ext_vector_type(8))) short short8;
typedef __attribute__((ext_vector_type(4))) float float4v;

__device__ __forceinline__ float fast_rcp(float x) {
    return __builtin_amdgcn_rcpf(x);
}
__device__ __forceinline__ float sigm(float x) {
    return fast_rcp(1.f + __expf(-x));
}
__device__ __forceinline__ float tanh_fast(float x) {
    return 1.f - 2.f * fast_rcp(1.f + __expf(2.f * x));
}
// bf16 RNE on raw bits (ties-to-even; NaN not expected here).
__device__ __forceinline__ unsigned cvt_rne(float f) {
    unsigned u = __float_as_uint(f);
    return (u + 0x7FFFu + ((u >> 16) & 1u)) >> 16;
}
__device__ __forceinline__ unsigned pack2(float a, float b) {
    return cvt_rne(a) | (cvt_rne(b) << 16);
}
__device__ __forceinline__ float bf_lo(unsigned u) {
    return __uint_as_float(u << 16);
}
__device__ __forceinline__ float bf_hi(unsigned u) {
    return __uint_as_float(u & 0xffff0000u);
}

// P[t][n][o] = sum_c x[n][t][c] * conv_w[o][c], stored bf16 (128B rows).
// Block 0 pre-converts w_ih/w_hh to bf16 and precomputes the folded gate
// bias (b_ih + b_hh + conv_b @ w_ih^T).
__global__ __launch_bounds__(256) void proj_kernel(
    const float* __restrict__ x, const float* __restrict__ conv_w,
    const float* __restrict__ conv_b, const float* __restrict__ w_ih,
    const float* __restrict__ w_hh, const float* __restrict__ b_ih,
    const float* __restrict__ b_hh,
    __hip_bfloat16* __restrict__ P, unsigned short* __restrict__ wihb,
    unsigned short* __restrict__ whhb, float* __restrict__ biasT)
{
    const int tid = threadIdx.x;
    if (blockIdx.x == 0) {   // prep block
        for (int e = tid; e < 4 * OO * OO; e += 256) {
            wihb[e] = (unsigned short)cvt_rne(w_ih[e]);
            whhb[e] = (unsigned short)cvt_rne(w_hh[e]);
        }
        float bj = b_ih[tid] + b_hh[tid];
        #pragma unroll
        for (int o = 0; o < OO; o += 4) {
            float4 cb = *(const float4*)(conv_b + o);
            float4 wr = *(const float4*)(w_ih + (size_t)tid * OO + o);
            bj = fmaf(cb.x, wr.x, bj); bj = fmaf(cb.y, wr.y, bj);
            bj = fmaf(cb.z, wr.z, bj); bj = fmaf(cb.w, wr.w, bj);
        }
        biasT[tid] = bj;
        return;
    }
    const int lane = tid & 63;
    const int wv = tid >> 6;
    float w[CC];
    #pragma unroll
    for (int c = 0; c < CC; c += 4) {
        float4 v = *(const float4*)(conv_w + lane * CC + c);
        w[c] = v.x; w[c + 1] = v.y; w[c + 2] = v.z; w[c + 3] = v.w;
    }
    const int rbase = (blockIdx.x - 1) * 16 + wv * 4;
    #pragma unroll
    for (int i = 0; i < 4; ++i) {
        int r = rbase + i;                    // r = n*TT + t (x row order)
        const float* xr = x + (size_t)r * CC;
        float a0 = 0.f, a1 = 0.f;
        #pragma unroll
        for (int c = 0; c < CC; c += 8) {
            float4 v = *(const float4*)(xr + c);
            float4 u = *(const float4*)(xr + c + 4);
            a0 = fmaf(v.x, w[c], a0);     a0 = fmaf(v.y, w[c + 1], a0);
            a0 = fmaf(v.z, w[c + 2], a0); a0 = fmaf(v.w, w[c + 3], a0);
            a1 = fmaf(u.x, w[c + 4], a1); a1 = fmaf(u.y, w[c + 5], a1);
            a1 = fmaf(u.z, w[c + 6], a1); a1 = fmaf(u.w, w[c + 7], a1);
        }
        int n = r / TT;
        int t = r - n * TT;
        ((unsigned short*)P)[(((size_t)t << 11) + n) * OO + lane] =
            (unsigned short)cvt_rne(a0 + a1);
    }
}

// Pure gather-max kernel. Single change vs the proven R2 version:
// __launch_bounds__(256, 8) — the body already fits exactly 64 VGPR
// (the 8-waves/SIMD cap), so occupancy doubles from 16 to 32 waves/CU,
// doubling the number of in-flight random-load batches per SIMD.
__global__ __launch_bounds__(256, 8) void gather_kernel(
    const __hip_bfloat16* __restrict__ P, const int* __restrict__ A,
    unsigned* __restrict__ featw)
{
    __shared__ int A_sh[4][128];            // per-wave: 4 rows x 32 idx
    const int tid = threadIdx.x;
    const int lane = tid & 63;
    const int wv = tid >> 6;
    const int bs = (blockIdx.x & 7) * 320 + (blockIdx.x >> 3);  // XCD swizzle
    const int r0 = bs << 4;                 // 16 rows/block, r = t*NA + n
    const int t = r0 >> 11;                 // block never crosses a t-slab
    const unsigned short* Pt = (const unsigned short*)P + ((size_t)t << 17);

    const int rw = r0 + wv * 4;             // wave's first row
    // stage this wave's 4 A-rows (128 ints) wave-locally; same-wave DS
    // ordering makes the later reads safe without a barrier.
    ((int2*)A_sh[wv])[lane] = ((const int2*)(A + ((size_t)rw << 5)))[lane];

    const int i_row = lane >> 4;            // 0..3: row within wave
    const int oc8 = lane & 15;              // 8B chunk (4 channels)
    const char* plane = (const char*)Pt + oc8 * 8;
    const int* myA = &A_sh[wv][i_row * 32];

    const int nself = (rw + i_row) & (NA - 1);
    const uint2 su = *(const uint2*)(plane + ((size_t)nself << 7));

    float m0 = -INFINITY, m1 = -INFINITY, m2 = -INFINITY, m3 = -INFINITY;
    #pragma unroll
    for (int bb = 0; bb < 2; ++bb) {
        int idx[16];
        #pragma unroll
        for (int g = 0; g < 16; ++g)        // broadcast ds_read_b32
            idx[g] = myA[bb * 16 + g];
        uint2 uv[16];                       // 32 VGPRs in-flight payload
        #pragma unroll
        for (int g = 0; g < 16; ++g)
            uv[g] = *(const uint2*)(plane + ((size_t)idx[g] << 7));
        #pragma unroll
        for (int g = 0; g < 16; ++g) {
            m0 = fmaxf(m0, bf_lo(uv[g].x)); m1 = fmaxf(m1, bf_hi(uv[g].x));
            m2 = fmaxf(m2, bf_lo(uv[g].y)); m3 = fmaxf(m3, bf_hi(uv[g].y));
        }
    }
    uint2 pk;
    pk.x = pack2(m0 - bf_lo(su.x), m1 - bf_hi(su.x));
    pk.y = pack2(m2 - bf_lo(su.y), m3 - bf_hi(su.y));
    *(uint2*)&featw[((size_t)(rw + i_row) << 5) + oc8 * 2] = pk;
}

// LSTM, channel-slice wave layout (proven R2 body): wave wv computes gate
// tiles {i,f,g,o} x (cols wv*16..wv*16+15), so lane l holds all 4 gates
// of agent (l>>4)*4+rg at channel wv*16+(l&15) -> pointwise fully
// in-register. One barrier per step; h_sh double-buffered.
__global__ __launch_bounds__(256) void lstm_kernel(
    const unsigned short* __restrict__ feat,
    const unsigned short* __restrict__ wihb,
    const unsigned short* __restrict__ whhb,
    const float* __restrict__ biasT, float* __restrict__ out)
{
    const int tid = threadIdx.x;
    const int lane = tid & 63;
    const int wv = tid >> 6;          // channel slice
    const int l15 = lane & 15;
    const int q = lane >> 4;
    const int a0 = blockIdx.x * 16;
    const int ch = wv * 16 + l15;     // this lane's gate/hidden channel

    // B-frags: gate g tile needs w rows g*64+ch (bf16, preconverted).
    short8 bfI[4][2], bfH[4][2];
    #pragma unroll
    for (int g = 0; g < 4; ++g) {
        int row = g * 64 + ch;
        #pragma unroll
        for (int ks = 0; ks < 2; ++ks) {
            bfI[g][ks] =
                *(const short8*)(wihb + ((size_t)row << 6) + ks * 32 + q * 8);
            bfH[g][ks] =
                *(const short8*)(whhb + ((size_t)row << 6) + ks * 32 + q * 8);
        }
    }
    float bias_g[4];
    #pragma unroll
    for (int g = 0; g < 4; ++g)
        bias_g[g] = biasT[g * 64 + ch];

    __shared__ __align__(16) unsigned short h_sh[2][16 * 72];  // dbuf, pad 72

    // zero h_sh[0]
    for (int e = tid; e < 16 * 72 / 2; e += 256)
        ((unsigned*)h_sh[0])[e] = 0u;

    float cst[4] = {0.f, 0.f, 0.f, 0.f};

    // preload feat A-frags for t = 0 (row = agent a0+l15)
    short8 ff[2];
    #pragma unroll
    for (int ks = 0; ks < 2; ++ks)
        ff[ks] = *(const short8*)(
            feat + (((size_t)a0 + l15) << 6) + ks * 32 + q * 8);

    __syncthreads();  // h_sh[0] ready

    for (int t = 0; t < TT; ++t) {
        // A-frag of h from the current buffer
        short8 ah[2];
        #pragma unroll
        for (int ks = 0; ks < 2; ++ks)
            ah[ks] = *(const short8*)(
                &h_sh[t & 1][l15 * 72 + ks * 32 + q * 8]);

        float4v acc[4] = {{0.f, 0.f, 0.f, 0.f}, {0.f, 0.f, 0.f, 0.f},
                          {0.f, 0.f, 0.f, 0.f}, {0.f, 0.f, 0.f, 0.f}};
        #pragma unroll
        for (int ks = 0; ks < 2; ++ks) {
            #pragma unroll
            for (int g = 0; g < 4; ++g) {
                acc[g] = __builtin_amdgcn_mfma_f32_16x16x32_bf16(
                    ff[ks], bfI[g][ks], acc[g], 0, 0, 0);
                acc[g] = __builtin_amdgcn_mfma_f32_16x16x32_bf16(
                    ah[ks], bfH[g][ks], acc[g], 0, 0, 0);
            }
        }

        // prefetch next step's feat frags while MFMAs drain
        short8 ffn[2];
        int tn = (t + 1 < TT) ? t + 1 : t;
        #pragma unroll
        for (int ks = 0; ks < 2; ++ks)
            ffn[ks] = *(const short8*)(
                feat + ((((size_t)tn << 11) + a0 + l15) << 6) + ks * 32 + q * 8);

        // pointwise fully in-register: lane holds i/f/g/o for
        // agent q*4+rg at channel ch.
        #pragma unroll
        for (int rg = 0; rg < 4; ++rg) {
            float gi = acc[0][rg] + bias_g[0];
            float gf = acc[1][rg] + bias_g[1];
            float gz = acc[2][rg] + bias_g[2];
            float go = acc[3][rg] + bias_g[3];
            float ig = sigm(gi);
            float fg = sigm(gf);
            float zg = tanh_fast(gz);
            float og = sigm(go);
            cst[rg] = fmaf(fg, cst[rg], ig * zg);
            float hv = og * tanh_fast(cst[rg]);
            int agent = q * 4 + rg;
            h_sh[(t + 1) & 1][agent * 72 + ch] = (unsigned short)cvt_rne(hv);
            out[(((size_t)(a0 + agent) * TT + t) << 6) + ch] = hv;
            if (t == TT - 1) {
                size_t hb = (size_t)NA * TT * OO;
                out[hb + ((size_t)(a0 + agent) << 6) + ch] = hv;
                out[hb + ((size_t)NA << 6) + ((size_t)(a0 + agent) << 6) + ch] =
                    cst[rg];
            }
        }
        __syncthreads();  // h_sh[(t+1)&1] ready for everyone
        ff[0] = ffn[0]; ff[1] = ffn[1];
    }
}

extern "C" void kernel_launch(void* const* d_in, const int* in_sizes, int n_in,
                              void* d_out, int out_size, void* d_ws, size_t ws_size,
                              hipStream_t stream) {
    const float* x      = (const float*)d_in[0];
    const int*   A      = (const int*)  d_in[1];
    const float* conv_w = (const float*)d_in[2];
    const float* conv_b = (const float*)d_in[3];
    const float* w_ih   = (const float*)d_in[4];
    const float* w_hh   = (const float*)d_in[5];
    const float* b_ih   = (const float*)d_in[6];
    const float* b_hh   = (const float*)d_in[7];
    float* out = (float*)d_out;

    char* ws = (char*)d_ws;
    __hip_bfloat16* P  = (__hip_bfloat16*)ws;                    // 5.25 MB
    size_t offF = (size_t)TT * NA * OO * 2;
    unsigned* featw = (unsigned*)(ws + offF);                    // 5.25 MB
    size_t offW = offF + (size_t)TT * NA * OO * 2;
    unsigned short* wihb = (unsigned short*)(ws + offW);         // 32 KB
    unsigned short* whhb = wihb + 4 * OO * OO;                   // 32 KB
    float* biasT = (float*)(whhb + 4 * OO * OO);                 // 1 KB

    hipLaunchKernelGGL(proj_kernel, dim3(NA * TT / 16 + 1), dim3(256), 0, stream,
                       x, conv_w, conv_b, w_ih, w_hh, b_ih, b_hh,
                       P, wihb, whhb, biasT);
    hipLaunchKernelGGL(gather_kernel, dim3(NA * TT / 16), dim3(256), 0, stream,
                       P, A, featw);
    hipLaunchKernelGGL(lstm_kernel, dim3(NA / 16), dim3(256), 0, stream,
                       (const unsigned short*)featw, wihb, whhb, biasT, out);
}

// Round 8
// 130.675 us; speedup vs baseline: 1.9280x; 1.0202x over previous
//
#include <hip/hip_runtime.h>
#include <hip/hip_bf16.h>
#include <math.h>

#define NA 2048   // agents (2^11)
#define TT 20     // timesteps
#define KK 32     // neighbors
#define CC 32     // in channels
#define OO 64     // out channels / hidden
#define GG 256    // 4*OO gates

typedef __attribute__((ext_vector_type(8))) short short8;
typedef __attribute__((ext_vector_type(4))) float float4v;

__device__ __forceinline__ float fast_rcp(float x) {
    return __builtin_amdgcn_rcpf(x);
}
__device__ __forceinline__ float sigm(float x) {
    return fast_rcp(1.f + __expf(-x));
}
__device__ __forceinline__ float tanh_fast(float x) {
    return 1.f - 2.f * fast_rcp(1.f + __expf(2.f * x));
}
// bf16 RNE on raw bits (ties-to-even; NaN not expected here).
__device__ __forceinline__ unsigned cvt_rne(float f) {
    unsigned u = __float_as_uint(f);
    return (u + 0x7FFFu + ((u >> 16) & 1u)) >> 16;
}
__device__ __forceinline__ unsigned pack2(float a, float b) {
    return cvt_rne(a) | (cvt_rne(b) << 16);
}
__device__ __forceinline__ float bf_lo(unsigned u) {
    return __uint_as_float(u << 16);
}
__device__ __forceinline__ float bf_hi(unsigned u) {
    return __uint_as_float(u & 0xffff0000u);
}

// P[t][n][o] = sum_c x[n][t][c] * conv_w[o][c], stored bf16 (128B rows).
// Block 0 pre-converts w_ih/w_hh to bf16 and precomputes the folded gate
// bias (b_ih + b_hh + conv_b @ w_ih^T).
__global__ __launch_bounds__(256) void proj_kernel(
    const float* __restrict__ x, const float* __restrict__ conv_w,
    const float* __restrict__ conv_b, const float* __restrict__ w_ih,
    const float* __restrict__ w_hh, const float* __restrict__ b_ih,
    const float* __restrict__ b_hh,
    __hip_bfloat16* __restrict__ P, unsigned short* __restrict__ wihb,
    unsigned short* __restrict__ whhb, float* __restrict__ biasT)
{
    const int tid = threadIdx.x;
    if (blockIdx.x == 0) {   // prep block
        for (int e = tid; e < 4 * OO * OO; e += 256) {
            wihb[e] = (unsigned short)cvt_rne(w_ih[e]);
            whhb[e] = (unsigned short)cvt_rne(w_hh[e]);
        }
        float bj = b_ih[tid] + b_hh[tid];
        #pragma unroll
        for (int o = 0; o < OO; o += 4) {
            float4 cb = *(const float4*)(conv_b + o);
            float4 wr = *(const float4*)(w_ih + (size_t)tid * OO + o);
            bj = fmaf(cb.x, wr.x, bj); bj = fmaf(cb.y, wr.y, bj);
            bj = fmaf(cb.z, wr.z, bj); bj = fmaf(cb.w, wr.w, bj);
        }
        biasT[tid] = bj;
        return;
    }
    const int lane = tid & 63;
    const int wv = tid >> 6;
    float w[CC];
    #pragma unroll
    for (int c = 0; c < CC; c += 4) {
        float4 v = *(const float4*)(conv_w + lane * CC + c);
        w[c] = v.x; w[c + 1] = v.y; w[c + 2] = v.z; w[c + 3] = v.w;
    }
    const int rbase = (blockIdx.x - 1) * 16 + wv * 4;
    #pragma unroll
    for (int i = 0; i < 4; ++i) {
        int r = rbase + i;                    // r = n*TT + t (x row order)
        const float* xr = x + (size_t)r * CC;
        float a0 = 0.f, a1 = 0.f;
        #pragma unroll
        for (int c = 0; c < CC; c += 8) {
            float4 v = *(const float4*)(xr + c);
            float4 u = *(const float4*)(xr + c + 4);
            a0 = fmaf(v.x, w[c], a0);     a0 = fmaf(v.y, w[c + 1], a0);
            a0 = fmaf(v.z, w[c + 2], a0); a0 = fmaf(v.w, w[c + 3], a0);
            a1 = fmaf(u.x, w[c + 4], a1); a1 = fmaf(u.y, w[c + 5], a1);
            a1 = fmaf(u.z, w[c + 6], a1); a1 = fmaf(u.w, w[c + 7], a1);
        }
        int n = r / TT;
        int t = r - n * TT;
        ((unsigned short*)P)[(((size_t)t << 11) + n) * OO + lane] =
            (unsigned short)cvt_rne(a0 + a1);
    }
}

// Pure gather-max kernel, proven R2 config: 4 rows/wave, dwordx2 per
// lane, 4 blocks/CU (R6 falsified the occupancy theory: 8 waves/SIMD
// was neutral-to-worse -> gather is L2 issue/BW-bound, not latency).
__global__ __launch_bounds__(256, 4) void gather_kernel(
    const __hip_bfloat16* __restrict__ P, const int* __restrict__ A,
    unsigned* __restrict__ featw)
{
    __shared__ int A_sh[4][128];            // per-wave: 4 rows x 32 idx
    const int tid = threadIdx.x;
    const int lane = tid & 63;
    const int wv = tid >> 6;
    const int bs = (blockIdx.x & 7) * 320 + (blockIdx.x >> 3);  // XCD swizzle
    const int r0 = bs << 4;                 // 16 rows/block, r = t*NA + n
    const int t = r0 >> 11;                 // block never crosses a t-slab
    const unsigned short* Pt = (const unsigned short*)P + ((size_t)t << 17);

    const int rw = r0 + wv * 4;             // wave's first row
    // stage this wave's 4 A-rows (128 ints) wave-locally; same-wave DS
    // ordering makes the later reads safe without a barrier.
    ((int2*)A_sh[wv])[lane] = ((const int2*)(A + ((size_t)rw << 5)))[lane];

    const int i_row = lane >> 4;            // 0..3: row within wave
    const int oc8 = lane & 15;              // 8B chunk (4 channels)
    const char* plane = (const char*)Pt + oc8 * 8;
    const int* myA = &A_sh[wv][i_row * 32];

    const int nself = (rw + i_row) & (NA - 1);
    const uint2 su = *(const uint2*)(plane + ((size_t)nself << 7));

    float m0 = -INFINITY, m1 = -INFINITY, m2 = -INFINITY, m3 = -INFINITY;
    #pragma unroll
    for (int bb = 0; bb < 2; ++bb) {
        int idx[16];
        #pragma unroll
        for (int g = 0; g < 16; ++g)        // broadcast ds_read_b32
            idx[g] = myA[bb * 16 + g];
        uint2 uv[16];                       // 32 VGPRs in-flight payload
        #pragma unroll
        for (int g = 0; g < 16; ++g)
            uv[g] = *(const uint2*)(plane + ((size_t)idx[g] << 7));
        #pragma unroll
        for (int g = 0; g < 16; ++g) {
            m0 = fmaxf(m0, bf_lo(uv[g].x)); m1 = fmaxf(m1, bf_hi(uv[g].x));
            m2 = fmaxf(m2, bf_lo(uv[g].y)); m3 = fmaxf(m3, bf_hi(uv[g].y));
        }
    }
    uint2 pk;
    pk.x = pack2(m0 - bf_lo(su.x), m1 - bf_hi(su.x));
    pk.y = pack2(m2 - bf_lo(su.y), m3 - bf_hi(su.y));
    *(uint2*)&featw[((size_t)(rw + i_row) << 5) + oc8 * 2] = pk;
}

// LSTM, channel-slice wave layout (proven R2 body): wave wv computes gate
// tiles {i,f,g,o} x (cols wv*16..wv*16+15), so lane l holds all 4 gates
// of agent (l>>4)*4+rg at channel wv*16+(l&15) -> pointwise fully
// in-register. One barrier per step; h_sh double-buffered.
__global__ __launch_bounds__(256) void lstm_kernel(
    const unsigned short* __restrict__ feat,
    const unsigned short* __restrict__ wihb,
    const unsigned short* __restrict__ whhb,
    const float* __restrict__ biasT, float* __restrict__ out)
{
    const int tid = threadIdx.x;
    const int lane = tid & 63;
    const int wv = tid >> 6;          // channel slice
    const int l15 = lane & 15;
    const int q = lane >> 4;
    const int a0 = blockIdx.x * 16;
    const int ch = wv * 16 + l15;     // this lane's gate/hidden channel

    // B-frags: gate g tile needs w rows g*64+ch (bf16, preconverted).
    short8 bfI[4][2], bfH[4][2];
    #pragma unroll
    for (int g = 0; g < 4; ++g) {
        int row = g * 64 + ch;
        #pragma unroll
        for (int ks = 0; ks < 2; ++ks) {
            bfI[g][ks] =
                *(const short8*)(wihb + ((size_t)row << 6) + ks * 32 + q * 8);
            bfH[g][ks] =
                *(const short8*)(whhb + ((size_t)row << 6) + ks * 32 + q * 8);
        }
    }
    float bias_g[4];
    #pragma unroll
    for (int g = 0; g < 4; ++g)
        bias_g[g] = biasT[g * 64 + ch];

    __shared__ __align__(16) unsigned short h_sh[2][16 * 72];  // dbuf, pad 72

    // zero h_sh[0]
    for (int e = tid; e < 16 * 72 / 2; e += 256)
        ((unsigned*)h_sh[0])[e] = 0u;

    float cst[4] = {0.f, 0.f, 0.f, 0.f};

    // preload feat A-frags for t = 0 (row = agent a0+l15)
    short8 ff[2];
    #pragma unroll
    for (int ks = 0; ks < 2; ++ks)
        ff[ks] = *(const short8*)(
            feat + (((size_t)a0 + l15) << 6) + ks * 32 + q * 8);

    __syncthreads();  // h_sh[0] ready

    for (int t = 0; t < TT; ++t) {
        // A-frag of h from the current buffer
        short8 ah[2];
        #pragma unroll
        for (int ks = 0; ks < 2; ++ks)
            ah[ks] = *(const short8*)(
                &h_sh[t & 1][l15 * 72 + ks * 32 + q * 8]);

        float4v acc[4] = {{0.f, 0.f, 0.f, 0.f}, {0.f, 0.f, 0.f, 0.f},
                          {0.f, 0.f, 0.f, 0.f}, {0.f, 0.f, 0.f, 0.f}};
        #pragma unroll
        for (int ks = 0; ks < 2; ++ks) {
            #pragma unroll
            for (int g = 0; g < 4; ++g) {
                acc[g] = __builtin_amdgcn_mfma_f32_16x16x32_bf16(
                    ff[ks], bfI[g][ks], acc[g], 0, 0, 0);
                acc[g] = __builtin_amdgcn_mfma_f32_16x16x32_bf16(
                    ah[ks], bfH[g][ks], acc[g], 0, 0, 0);
            }
        }

        // prefetch next step's feat frags while MFMAs drain
        short8 ffn[2];
        int tn = (t + 1 < TT) ? t + 1 : t;
        #pragma unroll
        for (int ks = 0; ks < 2; ++ks)
            ffn[ks] = *(const short8*)(
                feat + ((((size_t)tn << 11) + a0 + l15) << 6) + ks * 32 + q * 8);

        // pointwise fully in-register: lane holds i/f/g/o for
        // agent q*4+rg at channel ch.
        #pragma unroll
        for (int rg = 0; rg < 4; ++rg) {
            float gi = acc[0][rg] + bias_g[0];
            float gf = acc[1][rg] + bias_g[1];
            float gz = acc[2][rg] + bias_g[2];
            float go = acc[3][rg] + bias_g[3];
            float ig = sigm(gi);
            float fg = sigm(gf);
            float zg = tanh_fast(gz);
            float og = sigm(go);
            cst[rg] = fmaf(fg, cst[rg], ig * zg);
            float hv = og * tanh_fast(cst[rg]);
            int agent = q * 4 + rg;
            h_sh[(t + 1) & 1][agent * 72 + ch] = (unsigned short)cvt_rne(hv);
            out[(((size_t)(a0 + agent) * TT + t) << 6) + ch] = hv;
            if (t == TT - 1) {
                size_t hb = (size_t)NA * TT * OO;
                out[hb + ((size_t)(a0 + agent) << 6) + ch] = hv;
                out[hb + ((size_t)NA << 6) + ((size_t)(a0 + agent) << 6) + ch] =
                    cst[rg];
            }
        }
        __syncthreads();  // h_sh[(t+1)&1] ready for everyone
        ff[0] = ffn[0]; ff[1] = ffn[1];
    }
}

extern "C" void kernel_launch(void* const* d_in, const int* in_sizes, int n_in,
                              void* d_out, int out_size, void* d_ws, size_t ws_size,
                              hipStream_t stream) {
    const float* x      = (const float*)d_in[0];
    const int*   A      = (const int*)  d_in[1];
    const float* conv_w = (const float*)d_in[2];
    const float* conv_b = (const float*)d_in[3];
    const float* w_ih   = (const float*)d_in[4];
    const float* w_hh   = (const float*)d_in[5];
    const float* b_ih   = (const float*)d_in[6];
    const float* b_hh   = (const float*)d_in[7];
    float* out = (float*)d_out;

    char* ws = (char*)d_ws;
    __hip_bfloat16* P  = (__hip_bfloat16*)ws;                    // 5.25 MB
    size_t offF = (size_t)TT * NA * OO * 2;
    unsigned* featw = (unsigned*)(ws + offF);                    // 5.25 MB
    size_t offW = offF + (size_t)TT * NA * OO * 2;
    unsigned short* wihb = (unsigned short*)(ws + offW);         // 32 KB
    unsigned short* whhb = wihb + 4 * OO * OO;                   // 32 KB
    float* biasT = (float*)(whhb + 4 * OO * OO);                 // 1 KB

    hipLaunchKernelGGL(proj_kernel, dim3(NA * TT / 16 + 1), dim3(256), 0, stream,
                       x, conv_w, conv_b, w_ih, w_hh, b_ih, b_hh,
                       P, wihb, whhb, biasT);
    hipLaunchKernelGGL(gather_kernel, dim3(NA * TT / 16), dim3(256), 0, stream,
                       P, A, featw);
    hipLaunchKernelGGL(lstm_kernel, dim3(NA / 16), dim3(256), 0, stream,
                       (const unsigned short*)featw, wihb, whhb, biasT, out);
}